// Round 1
// baseline (1591.524 us; speedup 1.0000x reference)
//
#include <hip/hip_runtime.h>
#include <hip/hip_bf16.h>

// Problem constants (B=2, S=2048, D_MODEL=512, H=8, DEPTH=64)
constexpr int BATCH = 2;
constexpr int SEQ   = 2048;
constexpr int DM    = 512;
constexpr int NH    = 8;
constexpr int DP    = 64;
constexpr int MROWS = BATCH * SEQ;          // 4096
constexpr size_t HEADS_ELEMS = (size_t)BATCH * NH * SEQ * DP; // 2,097,152 floats

// ---------------------------------------------------------------------------
// Tiled fp32 GEMM: C[m,n] = (sum_k X[m,k]*W[n,k] + bias[n]) * scale
// X: [MROWS, 512] row-major, W: [512, 512] row-major (we dot along W rows,
// i.e. this computes X @ W^T which is exactly the reference's x @ Wq.T).
// MODE 0: write C flat [MROWS, 512]
// MODE 1: write head-split [B, H, S, DP]  (n0 block == head since BN==DP==64)
// ---------------------------------------------------------------------------
__global__ __launch_bounds__(256)
void gemm_xwt(const float* __restrict__ X, const float* __restrict__ W,
              const float* __restrict__ bias, float* __restrict__ C,
              float scale, int mode) {
    __shared__ float Xs[64][36];   // +4 pad: keeps 16B alignment for float4 LDS reads
    __shared__ float Ws[64][36];

    const int tid = threadIdx.x;
    const int tx = tid & 15;       // 0..15 -> output col group (tx*4 .. tx*4+3)
    const int ty = tid >> 4;       // 0..15 -> output rows ty + 16*i
    const int m0 = blockIdx.y * 64;
    const int n0 = blockIdx.x * 64;

    float acc[4][4];
    #pragma unroll
    for (int i = 0; i < 4; i++)
        #pragma unroll
        for (int j = 0; j < 4; j++) acc[i][j] = 0.f;

    for (int k0 = 0; k0 < DM; k0 += 32) {
        // stage 64x32 tiles of X and W (512 float4 each; 256 threads x 2)
        #pragma unroll
        for (int i = 0; i < 2; i++) {
            const int idx = tid + i * 256;   // float4 index
            const int row = idx >> 3;        // /8 float4s per 32-col row
            const int c   = (idx & 7) * 4;
            float4 xv = *(const float4*)(X + (size_t)(m0 + row) * DM + k0 + c);
            Xs[row][c + 0] = xv.x; Xs[row][c + 1] = xv.y;
            Xs[row][c + 2] = xv.z; Xs[row][c + 3] = xv.w;
            float4 wv = *(const float4*)(W + (size_t)(n0 + row) * DM + k0 + c);
            Ws[row][c + 0] = wv.x; Ws[row][c + 1] = wv.y;
            Ws[row][c + 2] = wv.z; Ws[row][c + 3] = wv.w;
        }
        __syncthreads();

        #pragma unroll
        for (int kk = 0; kk < 32; kk += 4) {
            float4 a[4], b[4];
            #pragma unroll
            for (int i = 0; i < 4; i++)
                a[i] = *(const float4*)&Xs[ty + 16 * i][kk];
            #pragma unroll
            for (int j = 0; j < 4; j++)
                b[j] = *(const float4*)&Ws[tx * 4 + j][kk];
            #pragma unroll
            for (int i = 0; i < 4; i++)
                #pragma unroll
                for (int j = 0; j < 4; j++)
                    acc[i][j] += a[i].x * b[j].x + a[i].y * b[j].y
                               + a[i].z * b[j].z + a[i].w * b[j].w;
        }
        __syncthreads();
    }

    // epilogue
    const int ncol = n0 + tx * 4;
    float4 bv = *(const float4*)(bias + ncol);
    #pragma unroll
    for (int i = 0; i < 4; i++) {
        const int m = m0 + ty + 16 * i;
        float4 out;
        out.x = (acc[i][0] + bv.x) * scale;
        out.y = (acc[i][1] + bv.y) * scale;
        out.z = (acc[i][2] + bv.z) * scale;
        out.w = (acc[i][3] + bv.w) * scale;
        if (mode == 0) {
            *(float4*)(C + (size_t)m * DM + ncol) = out;
        } else {
            // head-split: n0/64 == head h, d = tx*4..+3, b = m/SEQ, s = m%SEQ
            const int h = n0 >> 6;
            const int b = m >> 11;
            const int s = m & (SEQ - 1);
            float* dst = C + (((size_t)(b * NH + h) * SEQ + s) * DP) + tx * 4;
            *(float4*)dst = out;
        }
    }
}

// ---------------------------------------------------------------------------
// Flash attention, fp32 vector. One thread = one q row (q,o in registers).
// Block = 64 threads = 64 q rows of one (b,h). K/V tiles of 64 staged in LDS.
// Q is pre-scaled by 1/sqrt(DP) in the projection.
// Writes merged-head output [B, S, DM].
// ---------------------------------------------------------------------------
__global__ __launch_bounds__(64)
void attn_fwd(const float* __restrict__ Q, const float* __restrict__ K,
              const float* __restrict__ V, float* __restrict__ O) {
    __shared__ float ks[64][64];
    __shared__ float vs[64][64];

    const int tid = threadIdx.x;
    const int bh  = blockIdx.y;            // 0..15
    const int r   = blockIdx.x * 64 + tid; // q row within this head

    const float* qrow = Q + ((size_t)bh * SEQ + r) * DP;
    float q[DP];
    #pragma unroll
    for (int d4 = 0; d4 < 16; d4++) {
        float4 t = *(const float4*)(qrow + d4 * 4);
        q[d4 * 4 + 0] = t.x; q[d4 * 4 + 1] = t.y;
        q[d4 * 4 + 2] = t.z; q[d4 * 4 + 3] = t.w;
    }

    float o[DP];
    #pragma unroll
    for (int d = 0; d < DP; d++) o[d] = 0.f;
    float mrun = -1e30f, l = 0.f;

    const float* kb = K + (size_t)bh * SEQ * DP;
    const float* vb = V + (size_t)bh * SEQ * DP;

    for (int t0 = 0; t0 < SEQ; t0 += 64) {
        // stage K/V tile: 64 rows x 64 floats = 1024 float4 each
        const float4* kg = (const float4*)(kb + (size_t)t0 * DP);
        const float4* vg = (const float4*)(vb + (size_t)t0 * DP);
        float4* kls = (float4*)&ks[0][0];
        float4* vls = (float4*)&vs[0][0];
        #pragma unroll
        for (int i = 0; i < 16; i++) {
            const int idx = i * 64 + tid;
            kls[idx] = kg[idx];
            vls[idx] = vg[idx];
        }
        __syncthreads();

        for (int j = 0; j < 64; j++) {
            const float4* kj = (const float4*)&ks[j][0];
            float s0 = 0.f, s1 = 0.f, s2 = 0.f, s3 = 0.f;
            #pragma unroll
            for (int d4 = 0; d4 < 16; d4++) {
                float4 kvv = kj[d4];
                s0 += q[d4 * 4 + 0] * kvv.x;
                s1 += q[d4 * 4 + 1] * kvv.y;
                s2 += q[d4 * 4 + 2] * kvv.z;
                s3 += q[d4 * 4 + 3] * kvv.w;
            }
            const float sc = (s0 + s1) + (s2 + s3);

            if (sc > mrun) {             // rare after warm-up: defer-rescale
                const float f = __expf(mrun - sc);
                l *= f;
                #pragma unroll
                for (int d = 0; d < DP; d++) o[d] *= f;
                mrun = sc;
            }
            const float p = __expf(sc - mrun);
            l += p;
            const float4* vj = (const float4*)&vs[j][0];
            #pragma unroll
            for (int d4 = 0; d4 < 16; d4++) {
                float4 vv = vj[d4];
                o[d4 * 4 + 0] += p * vv.x;
                o[d4 * 4 + 1] += p * vv.y;
                o[d4 * 4 + 2] += p * vv.z;
                o[d4 * 4 + 3] += p * vv.w;
            }
        }
        __syncthreads();
    }

    const float inv = 1.f / l;
    const int b = bh >> 3, h = bh & 7;
    float* orow = O + ((size_t)(b * SEQ + r)) * DM + h * DP;
    #pragma unroll
    for (int d4 = 0; d4 < 16; d4++) {
        float4 t;
        t.x = o[d4 * 4 + 0] * inv; t.y = o[d4 * 4 + 1] * inv;
        t.z = o[d4 * 4 + 2] * inv; t.w = o[d4 * 4 + 3] * inv;
        *(float4*)(orow + d4 * 4) = t;
    }
}

// ---------------------------------------------------------------------------
extern "C" void kernel_launch(void* const* d_in, const int* in_sizes, int n_in,
                              void* d_out, int out_size, void* d_ws, size_t ws_size,
                              hipStream_t stream) {
    const float* x  = (const float*)d_in[0];
    const float* Wq = (const float*)d_in[1];
    const float* bq = (const float*)d_in[2];
    const float* Wk = (const float*)d_in[3];
    const float* bk = (const float*)d_in[4];
    const float* Wv = (const float*)d_in[5];
    const float* bv = (const float*)d_in[6];
    const float* Wo = (const float*)d_in[7];
    const float* bo = (const float*)d_in[8];
    float* out = (float*)d_out;

    float* ws = (float*)d_ws;
    float* qh = ws;                        // [B,H,S,DP]
    float* kh = ws + HEADS_ELEMS;
    float* vh = ws + 2 * HEADS_ELEMS;
    float* oh = ws + 3 * HEADS_ELEMS;      // merged [B,S,DM]

    const dim3 gGemm(DM / 64, MROWS / 64); // (8, 64)
    const dim3 bGemm(256);
    const float qscale = 0.125f;           // 1/sqrt(64)

    gemm_xwt<<<gGemm, bGemm, 0, stream>>>(x, Wq, bq, qh, qscale, 1);
    gemm_xwt<<<gGemm, bGemm, 0, stream>>>(x, Wk, bk, kh, 1.0f, 1);
    gemm_xwt<<<gGemm, bGemm, 0, stream>>>(x, Wv, bv, vh, 1.0f, 1);

    const dim3 gAttn(SEQ / 64, BATCH * NH); // (32, 16)
    attn_fwd<<<gAttn, dim3(64), 0, stream>>>(qh, kh, vh, oh);

    gemm_xwt<<<gGemm, bGemm, 0, stream>>>(oh, Wo, bo, out, 1.0f, 0);
}

// Round 2
// 283.857 us; speedup vs baseline: 5.6068x; 5.6068x over previous
//
#include <hip/hip_runtime.h>

typedef unsigned int  uint32;
typedef unsigned short ushort16;

constexpr int BATCH = 2;
constexpr int SEQ   = 2048;
constexpr int DM    = 512;
constexpr int NH    = 8;
constexpr int DP    = 64;
constexpr int MROWS = BATCH * SEQ;          // 4096
constexpr size_t HEADS_ELEMS = (size_t)BATCH * NH * SEQ * DP; // 2,097,152

typedef short bf16x8 __attribute__((ext_vector_type(8)));
typedef float f32x4  __attribute__((ext_vector_type(4)));
#define MFMA16(a, b, c) __builtin_amdgcn_mfma_f32_16x16x32_bf16((a), (b), (c), 0, 0, 0)

__device__ __forceinline__ ushort16 f2bf(float f) {
    uint32 u = __float_as_uint(f);
    uint32 r = (u + 0x7fffu + ((u >> 16) & 1u)) >> 16;
    return (ushort16)r;
}
__device__ __forceinline__ float bf2f(ushort16 u) {
    return __uint_as_float(((uint32)u) << 16);
}

// ---------------------------------------------------------------------------
// fp32-core GEMM: C[m,n] = (sum_k X[m,k]*W[n,k] + bias[n]) * scale
// XBF16: X is bf16 (ushort) instead of fp32.
// MODE 0: fp32 flat [M,512]   MODE 1: bf16 head-split [B,H,S,DP]
// MODE 2: bf16 head-split transposed [B,H,DP,S]
// ---------------------------------------------------------------------------
template <int XBF16, int MODE>
__global__ __launch_bounds__(256)
void gemm_xwt(const void* __restrict__ Xv, const float* __restrict__ W,
              const float* __restrict__ bias, void* __restrict__ Cv,
              float scale) {
    __shared__ float Xs[64][36];
    __shared__ float Ws[64][36];

    const int tid = threadIdx.x;
    const int tx = tid & 15;
    const int ty = tid >> 4;
    const int m0 = blockIdx.y * 64;
    const int n0 = blockIdx.x * 64;

    float acc[4][4];
    #pragma unroll
    for (int i = 0; i < 4; i++)
        #pragma unroll
        for (int j = 0; j < 4; j++) acc[i][j] = 0.f;

    for (int k0 = 0; k0 < DM; k0 += 32) {
        #pragma unroll
        for (int i = 0; i < 2; i++) {
            const int idx = tid + i * 256;
            const int row = idx >> 3;
            const int c   = (idx & 7) * 4;
            if (XBF16) {
                const ushort16* X = (const ushort16*)Xv;
                ushort4 xv = *(const ushort4*)(X + (size_t)(m0 + row) * DM + k0 + c);
                Xs[row][c + 0] = bf2f(xv.x); Xs[row][c + 1] = bf2f(xv.y);
                Xs[row][c + 2] = bf2f(xv.z); Xs[row][c + 3] = bf2f(xv.w);
            } else {
                const float* X = (const float*)Xv;
                float4 xv = *(const float4*)(X + (size_t)(m0 + row) * DM + k0 + c);
                Xs[row][c + 0] = xv.x; Xs[row][c + 1] = xv.y;
                Xs[row][c + 2] = xv.z; Xs[row][c + 3] = xv.w;
            }
            float4 wv = *(const float4*)(W + (size_t)(n0 + row) * DM + k0 + c);
            Ws[row][c + 0] = wv.x; Ws[row][c + 1] = wv.y;
            Ws[row][c + 2] = wv.z; Ws[row][c + 3] = wv.w;
        }
        __syncthreads();

        #pragma unroll
        for (int kk = 0; kk < 32; kk += 4) {
            float4 a[4], b[4];
            #pragma unroll
            for (int i = 0; i < 4; i++)
                a[i] = *(const float4*)&Xs[ty + 16 * i][kk];
            #pragma unroll
            for (int j = 0; j < 4; j++)
                b[j] = *(const float4*)&Ws[tx * 4 + j][kk];
            #pragma unroll
            for (int i = 0; i < 4; i++)
                #pragma unroll
                for (int j = 0; j < 4; j++)
                    acc[i][j] += a[i].x * b[j].x + a[i].y * b[j].y
                               + a[i].z * b[j].z + a[i].w * b[j].w;
        }
        __syncthreads();
    }

    const int ncol = n0 + tx * 4;
    float4 bv = *(const float4*)(bias + ncol);
    const float bias4[4] = {bv.x, bv.y, bv.z, bv.w};

    #pragma unroll
    for (int i = 0; i < 4; i++) {
        const int m = m0 + ty + 16 * i;
        float o[4];
        #pragma unroll
        for (int j = 0; j < 4; j++) o[j] = (acc[i][j] + bias4[j]) * scale;

        if (MODE == 0) {
            float4 out = {o[0], o[1], o[2], o[3]};
            *(float4*)((float*)Cv + (size_t)m * DM + ncol) = out;
        } else if (MODE == 1) {
            const int h = n0 >> 6;
            const int b = m >> 11;
            const int s = m & (SEQ - 1);
            ushort16* dst = (ushort16*)Cv + (((size_t)(b * NH + h) * SEQ + s) * DP) + tx * 4;
            ushort4 ob = {f2bf(o[0]), f2bf(o[1]), f2bf(o[2]), f2bf(o[3])};
            *(ushort4*)dst = ob;
        } else {  // MODE 2: [B,H,DP,S]
            const int h = n0 >> 6;
            const int b = m >> 11;
            const int s = m & (SEQ - 1);
            ushort16* base = (ushort16*)Cv + ((size_t)(b * NH + h) * DP) * SEQ;
            #pragma unroll
            for (int j = 0; j < 4; j++) {
                const int d = tx * 4 + j;
                base[(size_t)d * SEQ + s] = f2bf(o[j]);
            }
        }
    }
}

// ---------------------------------------------------------------------------
// MFMA bf16 flash attention.
// Block: 256 threads = 4 waves; each wave owns 16 q-rows; block = 64 q-rows.
// Q: bf16 [B,H,S,64] (pre-scaled by 1/8), K: bf16 [B,H,S,64], Vt: bf16 [B,H,64,S].
// Swapped QK^T: S^T = mfma(K_frag, Q_frag) -> lane owns one q-row (q = lane&15),
// k = sub*16 + (lane>>4)*4 + reg. Softmax reduce = shfl_xor 16,32.
// O acc layout: ok[c][reg] = O[q=(lane>>4)*4+reg][d = c*16 + (lane&15)].
// ---------------------------------------------------------------------------
__global__ __launch_bounds__(256)
void attn_mfma(const ushort16* __restrict__ Q, const ushort16* __restrict__ K,
               const ushort16* __restrict__ Vt, ushort16* __restrict__ O) {
    __shared__ ushort16 Kl[64][72];      // [k][d], padded
    __shared__ ushort16 Vl[64][72];      // [d][k], padded (V^T)
    __shared__ ushort16 Pl[4][16][72];   // per-wave P: [q][k], padded

    const int tid  = threadIdx.x;
    const int lane = tid & 63;
    const int wid  = tid >> 6;
    const int lg   = lane >> 4;   // lane group 0..3
    const int lq   = lane & 15;
    const int bh   = blockIdx.y;  // 0..15
    const int qt   = blockIdx.x;  // 0..31

    // Q fragments (B-operand: lane holds col q=lq, elems d = dc*32 + lg*8 + j)
    const int qrow = qt * 64 + wid * 16 + lq;
    const ushort16* qbase = Q + ((size_t)bh * SEQ + qrow) * DP;
    bf16x8 qf0 = *(const bf16x8*)(qbase + lg * 8);
    bf16x8 qf1 = *(const bf16x8*)(qbase + 32 + lg * 8);

    f32x4 ok[4];
    #pragma unroll
    for (int c = 0; c < 4; c++)
        #pragma unroll
        for (int r = 0; r < 4; r++) ok[c][r] = 0.f;
    float mrun = -1e30f, lrun = 0.f;

    const ushort16* kg = K  + (size_t)bh * SEQ * DP;   // [2048][64]
    const ushort16* vg = Vt + (size_t)bh * DP * SEQ;   // [64][2048]

    for (int t0 = 0; t0 < SEQ; t0 += 64) {
        // ---- stage K tile [64][64] and V^T tile [64][64] (bf16) ----
        #pragma unroll
        for (int i = 0; i < 2; i++) {
            const int ch  = tid + i * 256;
            const int row = ch >> 3;
            const int sl  = (ch & 7) * 8;
            *(uint4*)&Kl[row][sl] = *(const uint4*)(kg + (size_t)(t0 + row) * DP + sl);
            *(uint4*)&Vl[row][sl] = *(const uint4*)(vg + (size_t)row * SEQ + t0 + sl);
        }
        __syncthreads();

        // ---- S^T = K . Q^T : st[sub][reg] = S[q=lq][k = t0 + sub*16 + lg*4 + reg]
        f32x4 st[4];
        #pragma unroll
        for (int sub = 0; sub < 4; sub++) {
            #pragma unroll
            for (int r = 0; r < 4; r++) st[sub][r] = 0.f;
            bf16x8 k0 = *(const bf16x8*)&Kl[sub * 16 + lq][lg * 8];
            bf16x8 k1 = *(const bf16x8*)&Kl[sub * 16 + lq][32 + lg * 8];
            st[sub] = MFMA16(k0, qf0, st[sub]);
            st[sub] = MFMA16(k1, qf1, st[sub]);
        }

        // ---- online softmax (per q-row = lq, replicated across 4 lane groups)
        float tmax = st[0][0];
        #pragma unroll
        for (int sub = 0; sub < 4; sub++)
            #pragma unroll
            for (int r = 0; r < 4; r++) tmax = fmaxf(tmax, st[sub][r]);
        tmax = fmaxf(tmax, __shfl_xor(tmax, 16));
        tmax = fmaxf(tmax, __shfl_xor(tmax, 32));

        const float mnew = fmaxf(mrun, tmax);
        const float corr = __expf(mrun - mnew);
        float psum = 0.f;
        #pragma unroll
        for (int sub = 0; sub < 4; sub++) {
            #pragma unroll
            for (int r = 0; r < 4; r++) {
                const float p = __expf(st[sub][r] - mnew);
                st[sub][r] = p;
                psum += p;
            }
        }
        psum += __shfl_xor(psum, 16);
        psum += __shfl_xor(psum, 32);
        lrun = lrun * corr + psum;
        mrun = mnew;

        // ---- rescale O accumulators (per O-row q' = lg*4 + r)
        float cv[4];
        #pragma unroll
        for (int r = 0; r < 4; r++) cv[r] = __shfl(corr, lg * 4 + r);
        #pragma unroll
        for (int c = 0; c < 4; c++)
            #pragma unroll
            for (int r = 0; r < 4; r++) ok[c][r] *= cv[r];

        // ---- P -> bf16 -> per-wave LDS
        #pragma unroll
        for (int sub = 0; sub < 4; sub++) {
            uint2 w;
            w.x = (uint32)f2bf(st[sub][0]) | ((uint32)f2bf(st[sub][1]) << 16);
            w.y = (uint32)f2bf(st[sub][2]) | ((uint32)f2bf(st[sub][3]) << 16);
            *(uint2*)&Pl[wid][lq][sub * 16 + lg * 4] = w;
        }

        // ---- O += P . V   (A = P[16q x 32k], B = V[32k x 16d] from V^T rows)
        #pragma unroll
        for (int kc = 0; kc < 2; kc++) {
            bf16x8 pa = *(const bf16x8*)&Pl[wid][lq][kc * 32 + lg * 8];
            #pragma unroll
            for (int c = 0; c < 4; c++) {
                bf16x8 vb = *(const bf16x8*)&Vl[c * 16 + lq][kc * 32 + lg * 8];
                ok[c] = MFMA16(pa, vb, ok[c]);
            }
        }
        __syncthreads();
    }

    // ---- epilogue: normalize and write merged bf16 [B, S, DM]
    float linv[4];
    #pragma unroll
    for (int r = 0; r < 4; r++) linv[r] = 1.f / __shfl(lrun, lg * 4 + r);

    const int b = bh >> 3, h = bh & 7;
    #pragma unroll
    for (int c = 0; c < 4; c++) {
        #pragma unroll
        for (int r = 0; r < 4; r++) {
            const int qr = qt * 64 + wid * 16 + lg * 4 + r;
            O[((size_t)(b * SEQ + qr)) * DM + h * DP + c * 16 + lq] =
                f2bf(ok[c][r] * linv[r]);
        }
    }
}

// ---------------------------------------------------------------------------
extern "C" void kernel_launch(void* const* d_in, const int* in_sizes, int n_in,
                              void* d_out, int out_size, void* d_ws, size_t ws_size,
                              hipStream_t stream) {
    const float* x  = (const float*)d_in[0];
    const float* Wq = (const float*)d_in[1];
    const float* bq = (const float*)d_in[2];
    const float* Wk = (const float*)d_in[3];
    const float* bk = (const float*)d_in[4];
    const float* Wv = (const float*)d_in[5];
    const float* bv = (const float*)d_in[6];
    const float* Wo = (const float*)d_in[7];
    const float* bo = (const float*)d_in[8];
    float* out = (float*)d_out;

    ushort16* qh  = (ushort16*)d_ws;            // bf16 [B,H,S,DP]
    ushort16* kh  = qh  + HEADS_ELEMS;          // bf16 [B,H,S,DP]
    ushort16* vth = kh  + HEADS_ELEMS;          // bf16 [B,H,DP,S]
    ushort16* oh  = vth + HEADS_ELEMS;          // bf16 [B,S,DM]

    const dim3 gGemm(DM / 64, MROWS / 64);      // (8, 64)
    const dim3 bGemm(256);

    gemm_xwt<0, 1><<<gGemm, bGemm, 0, stream>>>(x, Wq, bq, qh, 0.125f);
    gemm_xwt<0, 1><<<gGemm, bGemm, 0, stream>>>(x, Wk, bk, kh, 1.0f);
    gemm_xwt<0, 2><<<gGemm, bGemm, 0, stream>>>(x, Wv, bv, vth, 1.0f);

    attn_mfma<<<dim3(SEQ / 64, BATCH * NH), dim3(256), 0, stream>>>(qh, kh, vth, oh);

    gemm_xwt<1, 0><<<gGemm, bGemm, 0, stream>>>(oh, Wo, bo, out, 1.0f);
}

// Round 3
// 100.491 us; speedup vs baseline: 15.8374x; 2.8247x over previous
//
#include <hip/hip_runtime.h>

typedef unsigned int   uint32;
typedef unsigned short ushort16;

constexpr int BATCH = 2;
constexpr int SEQ   = 2048;
constexpr int DM    = 512;
constexpr int NH    = 8;
constexpr int DP    = 64;
constexpr int MROWS = BATCH * SEQ;                              // 4096
constexpr size_t HEADS_ELEMS = (size_t)BATCH * NH * SEQ * DP;   // 2,097,152

typedef short bf16x8 __attribute__((ext_vector_type(8)));
typedef float f32x4  __attribute__((ext_vector_type(4)));
#define MFMA16(a, b, c) __builtin_amdgcn_mfma_f32_16x16x32_bf16((a), (b), (c), 0, 0, 0)

__device__ __forceinline__ ushort16 f2bf(float f) {
    uint32 u = __float_as_uint(f);
    uint32 r = (u + 0x7fffu + ((u >> 16) & 1u)) >> 16;
    return (ushort16)r;
}

__device__ __forceinline__ void gload16(const void* g, void* l) {
    __builtin_amdgcn_global_load_lds(
        (const __attribute__((address_space(1))) unsigned int*)g,
        (__attribute__((address_space(3))) unsigned int*)l, 16, 0, 0);
}

// ---------------------------------------------------------------------------
// Convert fp32 inputs to bf16 working buffers.
// x[2M] -> xb ; Wq,Wk,Wv -> wqkv (concat [1536][512]) ; Wo -> wob
// ---------------------------------------------------------------------------
constexpr int XF4 = (MROWS * DM) / 4;   // 524288
constexpr int WF4 = (DM * DM) / 4;      // 65536

__global__ __launch_bounds__(256)
void convert_inputs(const float4* __restrict__ x,  const float4* __restrict__ wq,
                    const float4* __restrict__ wk, const float4* __restrict__ wv,
                    const float4* __restrict__ wo, ushort4* __restrict__ xb,
                    ushort4* __restrict__ wqkv, ushort4* __restrict__ wob) {
    const int idx = blockIdx.x * 256 + threadIdx.x;
    float4 v; ushort4* dp;
    if (idx < XF4) { v = x[idx]; dp = xb + idx; }
    else {
        const int r = idx - XF4;
        if (r < WF4)          { v = wq[r];           dp = wqkv + r; }
        else if (r < 2 * WF4) { v = wk[r - WF4];     dp = wqkv + r; }
        else if (r < 3 * WF4) { v = wv[r - 2 * WF4]; dp = wqkv + r; }
        else                  { v = wo[r - 3 * WF4]; dp = wob + (r - 3 * WF4); }
    }
    ushort4 o = {f2bf(v.x), f2bf(v.y), f2bf(v.z), f2bf(v.w)};
    *dp = o;
}

// ---------------------------------------------------------------------------
// bf16 MFMA GEMM, m97-structure (BK=32, global_load_lds 16B, 4 waves 2x2).
// Computes C = X @ Wc^T (+bias) where X:[4096][512], Wc:[N][512] bf16.
// EPI 0 (QKV fused, N=1536): n<1024 -> Q/K via SWAPPED mfma (lane=col=s-dim,
//   regs=4 contig d) -> ushort4 into [B,H,S,64]; n>=1024 -> V via normal
//   orientation (regs=4 contig s) -> ushort4 into V^T [B,H,64,S].
// EPI 1 (O-proj, N=512): swapped, fp32 out [4096][512], float4 stores.
// ---------------------------------------------------------------------------
template <int BM, int BN, int EPI>
__global__ __launch_bounds__(256)
void gemm_mfma(const ushort16* __restrict__ X, const ushort16* __restrict__ Wc,
               const float* __restrict__ bq_, const float* __restrict__ bk_,
               const float* __restrict__ bv_, const float* __restrict__ bo_,
               ushort16* __restrict__ Qh, ushort16* __restrict__ Kh,
               ushort16* __restrict__ Vt, float* __restrict__ Out) {
    constexpr int FM = BM / 32;
    constexpr int FN = BN / 32;
    __shared__ ushort16 As[BM * 32];
    __shared__ ushort16 Bs[BN * 32];

    const int tid  = threadIdx.x;
    const int lane = tid & 63;
    const int wid  = tid >> 6;
    const int lg   = lane >> 4;
    const int lq   = lane & 15;
    const int wr   = wid >> 1;
    const int wc   = wid & 1;
    const int m0   = blockIdx.y * BM;
    const int n0   = blockIdx.x * BN;
    const bool swapped = (EPI == 1) || (n0 < 2 * DM);

    f32x4 acc[FM][FN];
    #pragma unroll
    for (int i = 0; i < FM; i++)
        #pragma unroll
        for (int j = 0; j < FN; j++)
            #pragma unroll
            for (int r = 0; r < 4; r++) acc[i][j][r] = 0.f;

    for (int k0 = 0; k0 < DM; k0 += 32) {
        #pragma unroll
        for (int i = 0; i < BM / 64; i++) {
            const int ch = tid + i * 256;
            const int row = ch >> 2, c8 = (ch & 3) * 8;
            gload16(X + (size_t)(m0 + row) * DM + k0 + c8, As + (size_t)ch * 8);
        }
        #pragma unroll
        for (int i = 0; i < BN / 64; i++) {
            const int ch = tid + i * 256;
            const int row = ch >> 2, c8 = (ch & 3) * 8;
            gload16(Wc + (size_t)(n0 + row) * DM + k0 + c8, Bs + (size_t)ch * 8);
        }
        __syncthreads();

        bf16x8 af[FM], bfr[FN];
        #pragma unroll
        for (int i = 0; i < FM; i++)
            af[i] = *(const bf16x8*)(As + (size_t)(wr * (BM / 2) + i * 16 + lq) * 32 + lg * 8);
        #pragma unroll
        for (int j = 0; j < FN; j++)
            bfr[j] = *(const bf16x8*)(Bs + (size_t)(wc * (BN / 2) + j * 16 + lq) * 32 + lg * 8);

        if (swapped) {
            #pragma unroll
            for (int i = 0; i < FM; i++)
                #pragma unroll
                for (int j = 0; j < FN; j++)
                    acc[i][j] = MFMA16(bfr[j], af[i], acc[i][j]);
        } else {
            #pragma unroll
            for (int i = 0; i < FM; i++)
                #pragma unroll
                for (int j = 0; j < FN; j++)
                    acc[i][j] = MFMA16(af[i], bfr[j], acc[i][j]);
        }
        __syncthreads();
    }

    if (EPI == 1) {
        // O-projection (swapped): lane col = m, regs = 4 contig n
        #pragma unroll
        for (int i = 0; i < FM; i++) {
            const int m = m0 + wr * (BM / 2) + i * 16 + lq;
            #pragma unroll
            for (int j = 0; j < FN; j++) {
                const int nr = n0 + wc * (BN / 2) + j * 16 + lg * 4;
                float4 b4 = *(const float4*)(bo_ + nr);
                float4 o;
                o.x = acc[i][j][0] + b4.x; o.y = acc[i][j][1] + b4.y;
                o.z = acc[i][j][2] + b4.z; o.w = acc[i][j][3] + b4.w;
                *(float4*)(Out + (size_t)m * DM + nr) = o;
            }
        }
    } else if (n0 < 2 * DM) {
        // Q / K (swapped): lane col = m(s), regs = 4 contig n(d)
        #pragma unroll
        for (int i = 0; i < FM; i++) {
            const int m = m0 + wr * (BM / 2) + i * 16 + lq;
            const int b = m >> 11, s = m & (SEQ - 1);
            #pragma unroll
            for (int j = 0; j < FN; j++) {
                const int nr = n0 + wc * (BN / 2) + j * 16 + lg * 4;
                const bool isq = nr < DM;
                const int rel = nr & (DM - 1);
                const int h = rel >> 6, d = rel & 63;
                float4 b4 = *(const float4*)((isq ? bq_ : bk_) + rel);
                const float sc = isq ? 0.125f : 1.0f;
                ushort4 o = { f2bf((acc[i][j][0] + b4.x) * sc),
                              f2bf((acc[i][j][1] + b4.y) * sc),
                              f2bf((acc[i][j][2] + b4.z) * sc),
                              f2bf((acc[i][j][3] + b4.w) * sc) };
                ushort16* dst = (isq ? Qh : Kh) +
                    (((size_t)(b * NH + h) * SEQ + s) * DP + d);
                *(ushort4*)dst = o;
            }
        }
    } else {
        // V (normal): lane col = n(d), regs = 4 contig m(s) -> V^T
        #pragma unroll
        for (int j = 0; j < FN; j++) {
            const int n = n0 + wc * (BN / 2) + j * 16 + lq;
            const int rel = n - 2 * DM;
            const int h = rel >> 6, d = rel & 63;
            const float bias = bv_[rel];
            #pragma unroll
            for (int i = 0; i < FM; i++) {
                const int mr = m0 + wr * (BM / 2) + i * 16 + lg * 4;
                const int b = mr >> 11, s0 = mr & (SEQ - 1);
                ushort4 o = { f2bf(acc[i][j][0] + bias),
                              f2bf(acc[i][j][1] + bias),
                              f2bf(acc[i][j][2] + bias),
                              f2bf(acc[i][j][3] + bias) };
                ushort16* dst = Vt +
                    (((size_t)(b * NH + h) * DP + d) * SEQ + s0);
                *(ushort4*)dst = o;
            }
        }
    }
}

// ---------------------------------------------------------------------------
// MFMA bf16 flash attention (unchanged from round 1; ~6 us).
// ---------------------------------------------------------------------------
__global__ __launch_bounds__(256)
void attn_mfma(const ushort16* __restrict__ Q, const ushort16* __restrict__ K,
               const ushort16* __restrict__ Vt, ushort16* __restrict__ O) {
    __shared__ ushort16 Kl[64][72];
    __shared__ ushort16 Vl[64][72];
    __shared__ ushort16 Pl[4][16][72];

    const int tid  = threadIdx.x;
    const int lane = tid & 63;
    const int wid  = tid >> 6;
    const int lg   = lane >> 4;
    const int lq   = lane & 15;
    const int bh   = blockIdx.y;
    const int qt   = blockIdx.x;

    const int qrow = qt * 64 + wid * 16 + lq;
    const ushort16* qbase = Q + ((size_t)bh * SEQ + qrow) * DP;
    bf16x8 qf0 = *(const bf16x8*)(qbase + lg * 8);
    bf16x8 qf1 = *(const bf16x8*)(qbase + 32 + lg * 8);

    f32x4 ok[4];
    #pragma unroll
    for (int c = 0; c < 4; c++)
        #pragma unroll
        for (int r = 0; r < 4; r++) ok[c][r] = 0.f;
    float mrun = -1e30f, lrun = 0.f;

    const ushort16* kg = K  + (size_t)bh * SEQ * DP;
    const ushort16* vg = Vt + (size_t)bh * DP * SEQ;

    for (int t0 = 0; t0 < SEQ; t0 += 64) {
        #pragma unroll
        for (int i = 0; i < 2; i++) {
            const int ch  = tid + i * 256;
            const int row = ch >> 3;
            const int sl  = (ch & 7) * 8;
            *(uint4*)&Kl[row][sl] = *(const uint4*)(kg + (size_t)(t0 + row) * DP + sl);
            *(uint4*)&Vl[row][sl] = *(const uint4*)(vg + (size_t)row * SEQ + t0 + sl);
        }
        __syncthreads();

        f32x4 st[4];
        #pragma unroll
        for (int sub = 0; sub < 4; sub++) {
            #pragma unroll
            for (int r = 0; r < 4; r++) st[sub][r] = 0.f;
            bf16x8 k0 = *(const bf16x8*)&Kl[sub * 16 + lq][lg * 8];
            bf16x8 k1 = *(const bf16x8*)&Kl[sub * 16 + lq][32 + lg * 8];
            st[sub] = MFMA16(k0, qf0, st[sub]);
            st[sub] = MFMA16(k1, qf1, st[sub]);
        }

        float tmax = st[0][0];
        #pragma unroll
        for (int sub = 0; sub < 4; sub++)
            #pragma unroll
            for (int r = 0; r < 4; r++) tmax = fmaxf(tmax, st[sub][r]);
        tmax = fmaxf(tmax, __shfl_xor(tmax, 16));
        tmax = fmaxf(tmax, __shfl_xor(tmax, 32));

        const float mnew = fmaxf(mrun, tmax);
        const float corr = __expf(mrun - mnew);
        float psum = 0.f;
        #pragma unroll
        for (int sub = 0; sub < 4; sub++) {
            #pragma unroll
            for (int r = 0; r < 4; r++) {
                const float p = __expf(st[sub][r] - mnew);
                st[sub][r] = p;
                psum += p;
            }
        }
        psum += __shfl_xor(psum, 16);
        psum += __shfl_xor(psum, 32);
        lrun = lrun * corr + psum;
        mrun = mnew;

        float cv[4];
        #pragma unroll
        for (int r = 0; r < 4; r++) cv[r] = __shfl(corr, lg * 4 + r);
        #pragma unroll
        for (int c = 0; c < 4; c++)
            #pragma unroll
            for (int r = 0; r < 4; r++) ok[c][r] *= cv[r];

        #pragma unroll
        for (int sub = 0; sub < 4; sub++) {
            uint2 w;
            w.x = (uint32)f2bf(st[sub][0]) | ((uint32)f2bf(st[sub][1]) << 16);
            w.y = (uint32)f2bf(st[sub][2]) | ((uint32)f2bf(st[sub][3]) << 16);
            *(uint2*)&Pl[wid][lq][sub * 16 + lg * 4] = w;
        }

        #pragma unroll
        for (int kc = 0; kc < 2; kc++) {
            bf16x8 pa = *(const bf16x8*)&Pl[wid][lq][kc * 32 + lg * 8];
            #pragma unroll
            for (int c = 0; c < 4; c++) {
                bf16x8 vb = *(const bf16x8*)&Vl[c * 16 + lq][kc * 32 + lg * 8];
                ok[c] = MFMA16(pa, vb, ok[c]);
            }
        }
        __syncthreads();
    }

    float linv[4];
    #pragma unroll
    for (int r = 0; r < 4; r++) linv[r] = 1.f / __shfl(lrun, lg * 4 + r);

    const int b = bh >> 3, h = bh & 7;
    #pragma unroll
    for (int c = 0; c < 4; c++) {
        #pragma unroll
        for (int r = 0; r < 4; r++) {
            const int qr = qt * 64 + wid * 16 + lg * 4 + r;
            O[((size_t)(b * SEQ + qr)) * DM + h * DP + c * 16 + lq] =
                f2bf(ok[c][r] * linv[r]);
        }
    }
}

// ---------------------------------------------------------------------------
extern "C" void kernel_launch(void* const* d_in, const int* in_sizes, int n_in,
                              void* d_out, int out_size, void* d_ws, size_t ws_size,
                              hipStream_t stream) {
    const float* x  = (const float*)d_in[0];
    const float* Wq = (const float*)d_in[1];
    const float* bq = (const float*)d_in[2];
    const float* Wk = (const float*)d_in[3];
    const float* bk = (const float*)d_in[4];
    const float* Wv = (const float*)d_in[5];
    const float* bv = (const float*)d_in[6];
    const float* Wo = (const float*)d_in[7];
    const float* bo = (const float*)d_in[8];
    float* out = (float*)d_out;

    ushort16* ws   = (ushort16*)d_ws;
    ushort16* xb   = ws;                                   // bf16 [4096][512]
    ushort16* wqkv = xb + (size_t)MROWS * DM;              // bf16 [1536][512]
    ushort16* wob  = wqkv + (size_t)3 * DM * DM;           // bf16 [512][512]
    ushort16* qh   = wob + (size_t)DM * DM;                // bf16 [B,H,S,64]
    ushort16* kh   = qh + HEADS_ELEMS;                     // bf16 [B,H,S,64]
    ushort16* vt   = kh + HEADS_ELEMS;                     // bf16 [B,H,64,S]
    ushort16* oh   = vt + HEADS_ELEMS;                     // bf16 [B,S,512]

    convert_inputs<<<dim3((XF4 + 4 * WF4) / 256), dim3(256), 0, stream>>>(
        (const float4*)x, (const float4*)Wq, (const float4*)Wk,
        (const float4*)Wv, (const float4*)Wo,
        (ushort4*)xb, (ushort4*)wqkv, (ushort4*)wob);

    gemm_mfma<128, 128, 0><<<dim3(12, 32), dim3(256), 0, stream>>>(
        xb, wqkv, bq, bk, bv, bo, qh, kh, vt, nullptr);

    attn_mfma<<<dim3(SEQ / 64, BATCH * NH), dim3(256), 0, stream>>>(qh, kh, vt, oh);

    gemm_mfma<64, 128, 1><<<dim3(4, 64), dim3(256), 0, stream>>>(
        oh, wob, bq, bk, bv, bo, qh, kh, vt, out);
}

// Round 4
// 93.908 us; speedup vs baseline: 16.9477x; 1.0701x over previous
//
#include <hip/hip_runtime.h>

typedef unsigned int   uint32;
typedef unsigned short ushort16;

constexpr int BATCH = 2;
constexpr int SEQ   = 2048;
constexpr int DM    = 512;
constexpr int NH    = 8;
constexpr int DP    = 64;
constexpr int MROWS = BATCH * SEQ;                              // 4096
constexpr size_t HEADS_ELEMS = (size_t)BATCH * NH * SEQ * DP;   // 2,097,152

typedef short bf16x8 __attribute__((ext_vector_type(8)));
typedef float f32x4  __attribute__((ext_vector_type(4)));
#define MFMA16(a, b, c) __builtin_amdgcn_mfma_f32_16x16x32_bf16((a), (b), (c), 0, 0, 0)

__device__ __forceinline__ ushort16 f2bf(float f) {
    uint32 u = __float_as_uint(f);
    uint32 r = (u + 0x7fffu + ((u >> 16) & 1u)) >> 16;
    return (ushort16)r;
}

__device__ __forceinline__ void gload16(const void* g, void* l) {
    __builtin_amdgcn_global_load_lds(
        (const __attribute__((address_space(1))) unsigned int*)g,
        (__attribute__((address_space(3))) unsigned int*)l, 16, 0, 0);
}

// ---------------------------------------------------------------------------
// Convert fp32 inputs to bf16 working buffers.
// ---------------------------------------------------------------------------
constexpr int XF4 = (MROWS * DM) / 4;   // 524288
constexpr int WF4 = (DM * DM) / 4;      // 65536

__global__ __launch_bounds__(256)
void convert_inputs(const float4* __restrict__ x,  const float4* __restrict__ wq,
                    const float4* __restrict__ wk, const float4* __restrict__ wv,
                    const float4* __restrict__ wo, ushort4* __restrict__ xb,
                    ushort4* __restrict__ wqkv, ushort4* __restrict__ wob) {
    const int idx = blockIdx.x * 256 + threadIdx.x;
    float4 v; ushort4* dp;
    if (idx < XF4) { v = x[idx]; dp = xb + idx; }
    else {
        const int r = idx - XF4;
        if (r < WF4)          { v = wq[r];           dp = wqkv + r; }
        else if (r < 2 * WF4) { v = wk[r - WF4];     dp = wqkv + r; }
        else if (r < 3 * WF4) { v = wv[r - 2 * WF4]; dp = wqkv + r; }
        else                  { v = wo[r - 3 * WF4]; dp = wob + (r - 3 * WF4); }
    }
    ushort4 o = {f2bf(v.x), f2bf(v.y), f2bf(v.z), f2bf(v.w)};
    *dp = o;
}

// ---------------------------------------------------------------------------
// bf16 MFMA GEMM (unchanged from round 2; correctness-verified).
// ---------------------------------------------------------------------------
template <int BM, int BN, int EPI>
__global__ __launch_bounds__(256)
void gemm_mfma(const ushort16* __restrict__ X, const ushort16* __restrict__ Wc,
               const float* __restrict__ bq_, const float* __restrict__ bk_,
               const float* __restrict__ bv_, const float* __restrict__ bo_,
               ushort16* __restrict__ Qh, ushort16* __restrict__ Kh,
               ushort16* __restrict__ Vt, float* __restrict__ Out) {
    constexpr int FM = BM / 32;
    constexpr int FN = BN / 32;
    __shared__ ushort16 As[BM * 32];
    __shared__ ushort16 Bs[BN * 32];

    const int tid  = threadIdx.x;
    const int lane = tid & 63;
    const int wid  = tid >> 6;
    const int lg   = lane >> 4;
    const int lq   = lane & 15;
    const int wr   = wid >> 1;
    const int wc   = wid & 1;
    const int m0   = blockIdx.y * BM;
    const int n0   = blockIdx.x * BN;
    const bool swapped = (EPI == 1) || (n0 < 2 * DM);

    f32x4 acc[FM][FN];
    #pragma unroll
    for (int i = 0; i < FM; i++)
        #pragma unroll
        for (int j = 0; j < FN; j++)
            #pragma unroll
            for (int r = 0; r < 4; r++) acc[i][j][r] = 0.f;

    for (int k0 = 0; k0 < DM; k0 += 32) {
        #pragma unroll
        for (int i = 0; i < BM / 64; i++) {
            const int ch = tid + i * 256;
            const int row = ch >> 2, c8 = (ch & 3) * 8;
            gload16(X + (size_t)(m0 + row) * DM + k0 + c8, As + (size_t)ch * 8);
        }
        #pragma unroll
        for (int i = 0; i < BN / 64; i++) {
            const int ch = tid + i * 256;
            const int row = ch >> 2, c8 = (ch & 3) * 8;
            gload16(Wc + (size_t)(n0 + row) * DM + k0 + c8, Bs + (size_t)ch * 8);
        }
        __syncthreads();

        bf16x8 af[FM], bfr[FN];
        #pragma unroll
        for (int i = 0; i < FM; i++)
            af[i] = *(const bf16x8*)(As + (size_t)(wr * (BM / 2) + i * 16 + lq) * 32 + lg * 8);
        #pragma unroll
        for (int j = 0; j < FN; j++)
            bfr[j] = *(const bf16x8*)(Bs + (size_t)(wc * (BN / 2) + j * 16 + lq) * 32 + lg * 8);

        if (swapped) {
            #pragma unroll
            for (int i = 0; i < FM; i++)
                #pragma unroll
                for (int j = 0; j < FN; j++)
                    acc[i][j] = MFMA16(bfr[j], af[i], acc[i][j]);
        } else {
            #pragma unroll
            for (int i = 0; i < FM; i++)
                #pragma unroll
                for (int j = 0; j < FN; j++)
                    acc[i][j] = MFMA16(af[i], bfr[j], acc[i][j]);
        }
        __syncthreads();
    }

    if (EPI == 1) {
        #pragma unroll
        for (int i = 0; i < FM; i++) {
            const int m = m0 + wr * (BM / 2) + i * 16 + lq;
            #pragma unroll
            for (int j = 0; j < FN; j++) {
                const int nr = n0 + wc * (BN / 2) + j * 16 + lg * 4;
                float4 b4 = *(const float4*)(bo_ + nr);
                float4 o;
                o.x = acc[i][j][0] + b4.x; o.y = acc[i][j][1] + b4.y;
                o.z = acc[i][j][2] + b4.z; o.w = acc[i][j][3] + b4.w;
                *(float4*)(Out + (size_t)m * DM + nr) = o;
            }
        }
    } else if (n0 < 2 * DM) {
        #pragma unroll
        for (int i = 0; i < FM; i++) {
            const int m = m0 + wr * (BM / 2) + i * 16 + lq;
            const int b = m >> 11, s = m & (SEQ - 1);
            #pragma unroll
            for (int j = 0; j < FN; j++) {
                const int nr = n0 + wc * (BN / 2) + j * 16 + lg * 4;
                const bool isq = nr < DM;
                const int rel = nr & (DM - 1);
                const int h = rel >> 6, d = rel & 63;
                float4 b4 = *(const float4*)((isq ? bq_ : bk_) + rel);
                const float sc = isq ? 0.125f : 1.0f;
                ushort4 o = { f2bf((acc[i][j][0] + b4.x) * sc),
                              f2bf((acc[i][j][1] + b4.y) * sc),
                              f2bf((acc[i][j][2] + b4.z) * sc),
                              f2bf((acc[i][j][3] + b4.w) * sc) };
                ushort16* dst = (isq ? Qh : Kh) +
                    (((size_t)(b * NH + h) * SEQ + s) * DP + d);
                *(ushort4*)dst = o;
            }
        }
    } else {
        #pragma unroll
        for (int j = 0; j < FN; j++) {
            const int n = n0 + wc * (BN / 2) + j * 16 + lq;
            const int rel = n - 2 * DM;
            const int h = rel >> 6, d = rel & 63;
            const float bias = bv_[rel];
            #pragma unroll
            for (int i = 0; i < FM; i++) {
                const int mr = m0 + wr * (BM / 2) + i * 16 + lg * 4;
                const int b = mr >> 11, s0 = mr & (SEQ - 1);
                ushort4 o = { f2bf(acc[i][j][0] + bias),
                              f2bf(acc[i][j][1] + bias),
                              f2bf(acc[i][j][2] + bias),
                              f2bf(acc[i][j][3] + bias) };
                ushort16* dst = Vt +
                    (((size_t)(b * NH + h) * DP + d) * SEQ + s0);
                *(ushort4*)dst = o;
            }
        }
    }
}

// ---------------------------------------------------------------------------
// MFMA bf16 flash attention v2.
//   - XOR-swizzled LDS (T2): logical [row][col8] at ushort off
//     row*64 + ((col8 ^ (row&7))*8); gload_lds keeps LINEAR dest, source
//     global address is inverse-swizzled (rule 21).
//   - 2-phase async double-buffer (T3/T4): stage t+1 before compute t,
//     raw s_barrier + one vmcnt(0) per tile.
//   - defer-max THR=8 (T13).
//   - XCD-aware block swizzle (T1): 512 blocks = 8 XCD x 64; 2 heads/XCD.
// ---------------------------------------------------------------------------
__global__ __launch_bounds__(256)
void attn_mfma(const ushort16* __restrict__ Q, const ushort16* __restrict__ K,
               const ushort16* __restrict__ Vt, ushort16* __restrict__ O) {
    __shared__ ushort16 Kl[2][64 * 64];
    __shared__ ushort16 Vl[2][64 * 64];
    __shared__ ushort16 Pl[4][16 * 64];

    const int tid  = threadIdx.x;
    const int lane = tid & 63;
    const int wid  = tid >> 6;
    const int lg   = lane >> 4;
    const int lq   = lane & 15;

    const int bid = blockIdx.x;                 // 0..511
    const int w   = (bid & 7) * 64 + (bid >> 3);// bijective (512 = 8*64)
    const int qt  = w & 31;
    const int bh  = w >> 5;

    // Q fragments
    const int qrow = qt * 64 + wid * 16 + lq;
    const ushort16* qbase = Q + ((size_t)bh * SEQ + qrow) * DP;
    bf16x8 qf0 = *(const bf16x8*)(qbase + lg * 8);
    bf16x8 qf1 = *(const bf16x8*)(qbase + 32 + lg * 8);

    f32x4 ok[4];
    #pragma unroll
    for (int c = 0; c < 4; c++)
        #pragma unroll
        for (int r = 0; r < 4; r++) ok[c][r] = 0.f;
    float mrun = -1e30f, lrun = 0.f;

    const ushort16* kg = K  + (size_t)bh * SEQ * DP;   // [2048][64]
    const ushort16* vg = Vt + (size_t)bh * DP * SEQ;   // [64][2048]
    ushort16* pl = &Pl[wid][0];

    // stage one 64-KV tile into buffer `buf` (linear LDS dest, swizzled src)
    auto stage = [&](int t0, int buf) {
        #pragma unroll
        for (int i = 0; i < 2; i++) {
            const int ch  = tid + i * 256;      // 0..511 : 16B slot index
            const int row = ch >> 3;
            const int cg  = ch & 7;
            const int sc  = (cg ^ (row & 7)) * 8;   // swizzled source col (ushorts)
            gload16(kg + (size_t)(t0 + row) * DP + sc, &Kl[buf][ch * 8]);
            gload16(vg + (size_t)row * SEQ + t0 + sc, &Vl[buf][ch * 8]);
        }
    };

    stage(0, 0);
    asm volatile("s_waitcnt vmcnt(0)" ::: "memory");
    __builtin_amdgcn_s_barrier();

    int cur = 0;
    for (int t0 = 0; t0 < SEQ; t0 += 64) {
        if (t0 + 64 < SEQ) stage(t0 + 64, cur ^ 1);

        const ushort16* kb = &Kl[cur][0];
        const ushort16* vb = &Vl[cur][0];

        // ---- S^T = K . Q^T : st[sub][r] = S[q=lq][k = sub*16 + lg*4 + r]
        f32x4 st[4];
        #pragma unroll
        for (int sub = 0; sub < 4; sub++) {
            #pragma unroll
            for (int r = 0; r < 4; r++) st[sub][r] = 0.f;
            const int row = sub * 16 + lq;
            bf16x8 k0 = *(const bf16x8*)(kb + row * 64 + ((lg ^ (row & 7)) * 8));
            bf16x8 k1 = *(const bf16x8*)(kb + row * 64 + (((4 + lg) ^ (row & 7)) * 8));
            st[sub] = MFMA16(k0, qf0, st[sub]);
            st[sub] = MFMA16(k1, qf1, st[sub]);
        }

        // ---- online softmax with defer-max (THR=8)
        float tmax = st[0][0];
        #pragma unroll
        for (int sub = 0; sub < 4; sub++)
            #pragma unroll
            for (int r = 0; r < 4; r++) tmax = fmaxf(tmax, st[sub][r]);
        tmax = fmaxf(tmax, __shfl_xor(tmax, 16));
        tmax = fmaxf(tmax, __shfl_xor(tmax, 32));

        if (!__all(tmax <= mrun + 8.f)) {       // wave-uniform branch
            const float mnew = fmaxf(mrun, tmax);
            const float corr = __expf(mrun - mnew);
            float cv[4];
            #pragma unroll
            for (int r = 0; r < 4; r++) cv[r] = __shfl(corr, lg * 4 + r);
            #pragma unroll
            for (int c = 0; c < 4; c++)
                #pragma unroll
                for (int r = 0; r < 4; r++) ok[c][r] *= cv[r];
            lrun *= corr;
            mrun = mnew;
        }

        float psum = 0.f;
        #pragma unroll
        for (int sub = 0; sub < 4; sub++) {
            #pragma unroll
            for (int r = 0; r < 4; r++) {
                const float p = __expf(st[sub][r] - mrun);
                st[sub][r] = p;
                psum += p;
            }
        }
        psum += __shfl_xor(psum, 16);
        psum += __shfl_xor(psum, 32);
        lrun += psum;

        // ---- P -> bf16 -> per-wave LDS (swizzled, 8B writes)
        #pragma unroll
        for (int sub = 0; sub < 4; sub++) {
            uint2 wv;
            wv.x = (uint32)f2bf(st[sub][0]) | ((uint32)f2bf(st[sub][1]) << 16);
            wv.y = (uint32)f2bf(st[sub][2]) | ((uint32)f2bf(st[sub][3]) << 16);
            const int cg = sub * 2 + (lg >> 1);
            *(uint2*)(pl + lq * 64 + ((cg ^ (lq & 7)) * 8) + (lg & 1) * 4) = wv;
        }

        // ---- O += P . V
        #pragma unroll
        for (int kc = 0; kc < 2; kc++) {
            bf16x8 pa = *(const bf16x8*)(pl + lq * 64 + (((kc * 4 + lg) ^ (lq & 7)) * 8));
            #pragma unroll
            for (int c = 0; c < 4; c++) {
                const int row = c * 16 + lq;
                bf16x8 vbf = *(const bf16x8*)(vb + row * 64 + (((kc * 4 + lg) ^ (row & 7)) * 8));
                ok[c] = MFMA16(pa, vbf, ok[c]);
            }
        }

        asm volatile("s_waitcnt vmcnt(0)" ::: "memory");
        __builtin_amdgcn_s_barrier();
        cur ^= 1;
    }

    // ---- epilogue
    float linv[4];
    #pragma unroll
    for (int r = 0; r < 4; r++) linv[r] = 1.f / __shfl(lrun, lg * 4 + r);

    const int b = bh >> 3, h = bh & 7;
    #pragma unroll
    for (int c = 0; c < 4; c++) {
        #pragma unroll
        for (int r = 0; r < 4; r++) {
            const int qr = qt * 64 + wid * 16 + lg * 4 + r;
            O[((size_t)(b * SEQ + qr)) * DM + h * DP + c * 16 + lq] =
                f2bf(ok[c][r] * linv[r]);
        }
    }
}

// ---------------------------------------------------------------------------
extern "C" void kernel_launch(void* const* d_in, const int* in_sizes, int n_in,
                              void* d_out, int out_size, void* d_ws, size_t ws_size,
                              hipStream_t stream) {
    const float* x  = (const float*)d_in[0];
    const float* Wq = (const float*)d_in[1];
    const float* bq = (const float*)d_in[2];
    const float* Wk = (const float*)d_in[3];
    const float* bk = (const float*)d_in[4];
    const float* Wv = (const float*)d_in[5];
    const float* bv = (const float*)d_in[6];
    const float* Wo = (const float*)d_in[7];
    const float* bo = (const float*)d_in[8];
    float* out = (float*)d_out;

    ushort16* ws   = (ushort16*)d_ws;
    ushort16* xb   = ws;
    ushort16* wqkv = xb + (size_t)MROWS * DM;
    ushort16* wob  = wqkv + (size_t)3 * DM * DM;
    ushort16* qh   = wob + (size_t)DM * DM;
    ushort16* kh   = qh + HEADS_ELEMS;
    ushort16* vt   = kh + HEADS_ELEMS;
    ushort16* oh   = vt + HEADS_ELEMS;

    convert_inputs<<<dim3((XF4 + 4 * WF4) / 256), dim3(256), 0, stream>>>(
        (const float4*)x, (const float4*)Wq, (const float4*)Wk,
        (const float4*)Wv, (const float4*)Wo,
        (ushort4*)xb, (ushort4*)wqkv, (ushort4*)wob);

    gemm_mfma<128, 128, 0><<<dim3(12, 32), dim3(256), 0, stream>>>(
        xb, wqkv, bq, bk, bv, bo, qh, kh, vt, nullptr);

    attn_mfma<<<dim3(512), dim3(256), 0, stream>>>(qh, kh, vt, oh);

    gemm_mfma<64, 128, 1><<<dim3(4, 64), dim3(256), 0, stream>>>(
        oh, wob, bq, bk, bv, bo, qh, kh, vt, out);
}

// Round 5
// 91.498 us; speedup vs baseline: 17.3940x; 1.0263x over previous
//
#include <hip/hip_runtime.h>

typedef unsigned int   uint32;
typedef unsigned short ushort16;

constexpr int BATCH = 2;
constexpr int SEQ   = 2048;
constexpr int DM    = 512;
constexpr int NH    = 8;
constexpr int DP    = 64;
constexpr int MROWS = BATCH * SEQ;                              // 4096
constexpr size_t HEADS_ELEMS = (size_t)BATCH * NH * SEQ * DP;   // 2,097,152

typedef short bf16x8 __attribute__((ext_vector_type(8)));
typedef float f32x4  __attribute__((ext_vector_type(4)));
#define MFMA16(a, b, c) __builtin_amdgcn_mfma_f32_16x16x32_bf16((a), (b), (c), 0, 0, 0)

__device__ __forceinline__ ushort16 f2bf(float f) {
    uint32 u = __float_as_uint(f);
    uint32 r = (u + 0x7fffu + ((u >> 16) & 1u)) >> 16;
    return (ushort16)r;
}

__device__ __forceinline__ uint32 cvtpk(float a, float b) {
    uint32 r;
    asm("v_cvt_pk_bf16_f32 %0, %1, %2" : "=v"(r) : "v"(a), "v"(b));
    return r;
}

__device__ __forceinline__ void gload16(const void* g, void* l) {
    __builtin_amdgcn_global_load_lds(
        (const __attribute__((address_space(1))) unsigned int*)g,
        (__attribute__((address_space(3))) unsigned int*)l, 16, 0, 0);
}

// ---------------------------------------------------------------------------
// Convert fp32 inputs to bf16 working buffers.
// ---------------------------------------------------------------------------
constexpr int XF4 = (MROWS * DM) / 4;   // 524288
constexpr int WF4 = (DM * DM) / 4;      // 65536

__global__ __launch_bounds__(256)
void convert_inputs(const float4* __restrict__ x,  const float4* __restrict__ wq,
                    const float4* __restrict__ wk, const float4* __restrict__ wv,
                    const float4* __restrict__ wo, ushort4* __restrict__ xb,
                    ushort4* __restrict__ wqkv, ushort4* __restrict__ wob) {
    const int idx = blockIdx.x * 256 + threadIdx.x;
    float4 v; ushort4* dp;
    if (idx < XF4) { v = x[idx]; dp = xb + idx; }
    else {
        const int r = idx - XF4;
        if (r < WF4)          { v = wq[r];           dp = wqkv + r; }
        else if (r < 2 * WF4) { v = wk[r - WF4];     dp = wqkv + r; }
        else if (r < 3 * WF4) { v = wv[r - 2 * WF4]; dp = wqkv + r; }
        else                  { v = wo[r - 3 * WF4]; dp = wob + (r - 3 * WF4); }
    }
    ushort4 o = {f2bf(v.x), f2bf(v.y), f2bf(v.z), f2bf(v.w)};
    *dp = o;
}

// ---------------------------------------------------------------------------
// bf16 MFMA GEMM (unchanged; correctness-verified).
// ---------------------------------------------------------------------------
template <int BM, int BN, int EPI>
__global__ __launch_bounds__(256)
void gemm_mfma(const ushort16* __restrict__ X, const ushort16* __restrict__ Wc,
               const float* __restrict__ bq_, const float* __restrict__ bk_,
               const float* __restrict__ bv_, const float* __restrict__ bo_,
               ushort16* __restrict__ Qh, ushort16* __restrict__ Kh,
               ushort16* __restrict__ Vt, float* __restrict__ Out) {
    constexpr int FM = BM / 32;
    constexpr int FN = BN / 32;
    __shared__ ushort16 As[BM * 32];
    __shared__ ushort16 Bs[BN * 32];

    const int tid  = threadIdx.x;
    const int lane = tid & 63;
    const int wid  = tid >> 6;
    const int lg   = lane >> 4;
    const int lq   = lane & 15;
    const int wr   = wid >> 1;
    const int wc   = wid & 1;
    const int m0   = blockIdx.y * BM;
    const int n0   = blockIdx.x * BN;
    const bool swapped = (EPI == 1) || (n0 < 2 * DM);

    f32x4 acc[FM][FN];
    #pragma unroll
    for (int i = 0; i < FM; i++)
        #pragma unroll
        for (int j = 0; j < FN; j++)
            #pragma unroll
            for (int r = 0; r < 4; r++) acc[i][j][r] = 0.f;

    for (int k0 = 0; k0 < DM; k0 += 32) {
        #pragma unroll
        for (int i = 0; i < BM / 64; i++) {
            const int ch = tid + i * 256;
            const int row = ch >> 2, c8 = (ch & 3) * 8;
            gload16(X + (size_t)(m0 + row) * DM + k0 + c8, As + (size_t)ch * 8);
        }
        #pragma unroll
        for (int i = 0; i < BN / 64; i++) {
            const int ch = tid + i * 256;
            const int row = ch >> 2, c8 = (ch & 3) * 8;
            gload16(Wc + (size_t)(n0 + row) * DM + k0 + c8, Bs + (size_t)ch * 8);
        }
        __syncthreads();

        bf16x8 af[FM], bfr[FN];
        #pragma unroll
        for (int i = 0; i < FM; i++)
            af[i] = *(const bf16x8*)(As + (size_t)(wr * (BM / 2) + i * 16 + lq) * 32 + lg * 8);
        #pragma unroll
        for (int j = 0; j < FN; j++)
            bfr[j] = *(const bf16x8*)(Bs + (size_t)(wc * (BN / 2) + j * 16 + lq) * 32 + lg * 8);

        if (swapped) {
            #pragma unroll
            for (int i = 0; i < FM; i++)
                #pragma unroll
                for (int j = 0; j < FN; j++)
                    acc[i][j] = MFMA16(bfr[j], af[i], acc[i][j]);
        } else {
            #pragma unroll
            for (int i = 0; i < FM; i++)
                #pragma unroll
                for (int j = 0; j < FN; j++)
                    acc[i][j] = MFMA16(af[i], bfr[j], acc[i][j]);
        }
        __syncthreads();
    }

    if (EPI == 1) {
        #pragma unroll
        for (int i = 0; i < FM; i++) {
            const int m = m0 + wr * (BM / 2) + i * 16 + lq;
            #pragma unroll
            for (int j = 0; j < FN; j++) {
                const int nr = n0 + wc * (BN / 2) + j * 16 + lg * 4;
                float4 b4 = *(const float4*)(bo_ + nr);
                float4 o;
                o.x = acc[i][j][0] + b4.x; o.y = acc[i][j][1] + b4.y;
                o.z = acc[i][j][2] + b4.z; o.w = acc[i][j][3] + b4.w;
                *(float4*)(Out + (size_t)m * DM + nr) = o;
            }
        }
    } else if (n0 < 2 * DM) {
        #pragma unroll
        for (int i = 0; i < FM; i++) {
            const int m = m0 + wr * (BM / 2) + i * 16 + lq;
            const int b = m >> 11, s = m & (SEQ - 1);
            #pragma unroll
            for (int j = 0; j < FN; j++) {
                const int nr = n0 + wc * (BN / 2) + j * 16 + lg * 4;
                const bool isq = nr < DM;
                const int rel = nr & (DM - 1);
                const int h = rel >> 6, d = rel & 63;
                float4 b4 = *(const float4*)((isq ? bq_ : bk_) + rel);
                const float sc = isq ? 0.125f : 1.0f;
                ushort4 o = { f2bf((acc[i][j][0] + b4.x) * sc),
                              f2bf((acc[i][j][1] + b4.y) * sc),
                              f2bf((acc[i][j][2] + b4.z) * sc),
                              f2bf((acc[i][j][3] + b4.w) * sc) };
                ushort16* dst = (isq ? Qh : Kh) +
                    (((size_t)(b * NH + h) * SEQ + s) * DP + d);
                *(ushort4*)dst = o;
            }
        }
    } else {
        #pragma unroll
        for (int j = 0; j < FN; j++) {
            const int n = n0 + wc * (BN / 2) + j * 16 + lq;
            const int rel = n - 2 * DM;
            const int h = rel >> 6, d = rel & 63;
            const float bias = bv_[rel];
            #pragma unroll
            for (int i = 0; i < FM; i++) {
                const int mr = m0 + wr * (BM / 2) + i * 16 + lg * 4;
                const int b = mr >> 11, s0 = mr & (SEQ - 1);
                ushort4 o = { f2bf(acc[i][j][0] + bias),
                              f2bf(acc[i][j][1] + bias),
                              f2bf(acc[i][j][2] + bias),
                              f2bf(acc[i][j][3] + bias) };
                ushort16* dst = Vt +
                    (((size_t)(b * NH + h) * DP + d) * SEQ + s0);
                *(ushort4*)dst = o;
            }
        }
    }
}

// ---------------------------------------------------------------------------
// MFMA bf16 flash attention v3.
// Grid 1024 (XCD-swizzled): block = 32 q-rows of one (b,h). 256 thr = 4 waves:
// wave (qh_, kh_) = (wid&1, wid>>1): 16 q-rows x 32-k slice of each 64-KV tile.
// Per-wave online softmax over its k-slice; end-of-kernel (m,l,O) merge in LDS.
// LDS 40KB -> 4 blocks/CU (16 waves/CU). All swizzled LDS offsets and staging
// pointers hoisted; P pack via v_cvt_pk_bf16_f32; setprio around MFMA.
// ---------------------------------------------------------------------------
__global__ __launch_bounds__(256, 4)
void attn_mfma(const ushort16* __restrict__ Q, const ushort16* __restrict__ K,
               const ushort16* __restrict__ Vt, ushort16* __restrict__ O) {
    __shared__ ushort16 Kl[2][64 * 64];   // 16 KB
    __shared__ ushort16 Vl[2][64 * 64];   // 16 KB
    __shared__ ushort16 Pl[4][16 * 64];   // 8 KB

    const int tid  = threadIdx.x;
    const int lane = tid & 63;
    const int wid  = tid >> 6;
    const int lg   = lane >> 4;
    const int lq   = lane & 15;
    const int qh_  = wid & 1;    // q-half (rows qh_*16 .. +16)
    const int kh_  = wid >> 1;   // k-half (cols kh_*32 .. +32 of each tile)

    const int bid = blockIdx.x;                   // 0..1023
    const int w   = (bid & 7) * 128 + (bid >> 3); // 8 XCDs x 128 = 2 heads/XCD
    const int qt  = w & 63;
    const int bh  = w >> 6;

    // Q fragments (B-operand: lane holds col q=lq, elems d = lg*8+j)
    const int qrow = qt * 32 + qh_ * 16 + lq;
    const ushort16* qbase = Q + ((size_t)bh * SEQ + qrow) * DP;
    const bf16x8 qf0 = *(const bf16x8*)(qbase + lg * 8);
    const bf16x8 qf1 = *(const bf16x8*)(qbase + 32 + lg * 8);

    f32x4 ok[4];
    #pragma unroll
    for (int c = 0; c < 4; c++)
        #pragma unroll
        for (int r = 0; r < 4; r++) ok[c][r] = 0.f;
    float mrun = -1e30f, lrun = 0.f;

    // ---- hoisted staging pointers (advance by constant stride per tile) ----
    const ushort16* kg = K  + (size_t)bh * SEQ * DP;   // [2048][64]
    const ushort16* vg = Vt + (size_t)bh * DP * SEQ;   // [64][2048]
    {
    }
    const int r0 = tid >> 3,  c0 = tid & 7;
    const int r1 = r0 + 32,   c1 = c0;
    const int sc0 = (c0 ^ (r0 & 7)) * 8;
    const int sc1 = (c1 ^ (r1 & 7)) * 8;
    const ushort16* kp0 = kg + (size_t)r0 * DP + sc0;
    const ushort16* kp1 = kg + (size_t)r1 * DP + sc1;
    const ushort16* vp0 = vg + (size_t)r0 * SEQ + sc0;
    const ushort16* vp1 = vg + (size_t)r1 * SEQ + sc1;
    ushort16* const kA0 = &Kl[0][(size_t)tid * 8];
    ushort16* const kA1 = &Kl[0][(size_t)(tid + 256) * 8];
    ushort16* const kB0 = &Kl[1][(size_t)tid * 8];
    ushort16* const kB1 = &Kl[1][(size_t)(tid + 256) * 8];
    ushort16* const vA0 = &Vl[0][(size_t)tid * 8];
    ushort16* const vA1 = &Vl[0][(size_t)(tid + 256) * 8];
    ushort16* const vB0 = &Vl[1][(size_t)tid * 8];
    ushort16* const vB1 = &Vl[1][(size_t)(tid + 256) * 8];

    auto stageA = [&]() {
        gload16(kp0, kA0); gload16(kp1, kA1);
        gload16(vp0, vA0); gload16(vp1, vA1);
        kp0 += 64 * DP; kp1 += 64 * DP; vp0 += 64; vp1 += 64;
    };
    auto stageB = [&]() {
        gload16(kp0, kB0); gload16(kp1, kB1);
        gload16(vp0, vB0); gload16(vp1, vB1);
        kp0 += 64 * DP; kp1 += 64 * DP; vp0 += 64; vp1 += 64;
    };

    // ---- hoisted swizzled LDS read/write offsets (ushort units) ----
    const int lq7 = lq & 7;
    const int krow0 = kh_ * 32 + lq;
    const int krow1 = krow0 + 16;
    const int ko00 = krow0 * 64 + ((lg ^ lq7) * 8);
    const int ko01 = krow0 * 64 + (((4 + lg) ^ lq7) * 8);
    const int ko10 = krow1 * 64 + ((lg ^ lq7) * 8);
    const int ko11 = krow1 * 64 + (((4 + lg) ^ lq7) * 8);
    int vo[4];
    #pragma unroll
    for (int c = 0; c < 4; c++)
        vo[c] = (c * 16 + lq) * 64 + (((kh_ * 4 + lg) ^ lq7) * 8);
    ushort16* const pl = &Pl[wid][0];
    const int pw0 = lq * 64 + (((lg >> 1) ^ lq7) * 8) + (lg & 1) * 4;
    const int pw1 = lq * 64 + (((2 + (lg >> 1)) ^ lq7) * 8) + (lg & 1) * 4;
    const int pr  = lq * 64 + ((lg ^ lq7) * 8);
    const ushort16* const kbA = &Kl[0][0];
    const ushort16* const kbB = &Kl[1][0];
    const ushort16* const vbA = &Vl[0][0];
    const ushort16* const vbB = &Vl[1][0];

    auto compute = [&](const ushort16* kb, const ushort16* vb) {
        f32x4 st0, st1;
        #pragma unroll
        for (int r = 0; r < 4; r++) { st0[r] = 0.f; st1[r] = 0.f; }
        const bf16x8 k00 = *(const bf16x8*)(kb + ko00);
        const bf16x8 k01 = *(const bf16x8*)(kb + ko01);
        const bf16x8 k10 = *(const bf16x8*)(kb + ko10);
        const bf16x8 k11 = *(const bf16x8*)(kb + ko11);
        __builtin_amdgcn_s_setprio(1);
        st0 = MFMA16(k00, qf0, st0);
        st0 = MFMA16(k01, qf1, st0);
        st1 = MFMA16(k10, qf0, st1);
        st1 = MFMA16(k11, qf1, st1);
        __builtin_amdgcn_s_setprio(0);

        float tmax = fmaxf(fmaxf(fmaxf(st0[0], st0[1]), fmaxf(st0[2], st0[3])),
                           fmaxf(fmaxf(st1[0], st1[1]), fmaxf(st1[2], st1[3])));
        tmax = fmaxf(tmax, __shfl_xor(tmax, 16));
        tmax = fmaxf(tmax, __shfl_xor(tmax, 32));

        if (!__all(tmax <= mrun + 8.f)) {   // defer-max (THR=8), wave-uniform
            const float mnew = fmaxf(mrun, tmax);
            const float corr = __expf(mrun - mnew);
            float cv[4];
            #pragma unroll
            for (int r = 0; r < 4; r++) cv[r] = __shfl(corr, lg * 4 + r);
            #pragma unroll
            for (int c = 0; c < 4; c++)
                #pragma unroll
                for (int r = 0; r < 4; r++) ok[c][r] *= cv[r];
            lrun *= corr;
            mrun = mnew;
        }

        float psum = 0.f;
        #pragma unroll
        for (int r = 0; r < 4; r++) {
            st0[r] = __expf(st0[r] - mrun); psum += st0[r];
            st1[r] = __expf(st1[r] - mrun); psum += st1[r];
        }
        psum += __shfl_xor(psum, 16);
        psum += __shfl_xor(psum, 32);
        lrun += psum;

        uint2 w0, w1;
        w0.x = cvtpk(st0[0], st0[1]); w0.y = cvtpk(st0[2], st0[3]);
        w1.x = cvtpk(st1[0], st1[1]); w1.y = cvtpk(st1[2], st1[3]);
        *(uint2*)(pl + pw0) = w0;
        *(uint2*)(pl + pw1) = w1;

        const bf16x8 pa  = *(const bf16x8*)(pl + pr);
        const bf16x8 vb0 = *(const bf16x8*)(vb + vo[0]);
        const bf16x8 vb1 = *(const bf16x8*)(vb + vo[1]);
        const bf16x8 vb2 = *(const bf16x8*)(vb + vo[2]);
        const bf16x8 vb3 = *(const bf16x8*)(vb + vo[3]);
        __builtin_amdgcn_s_setprio(1);
        ok[0] = MFMA16(pa, vb0, ok[0]);
        ok[1] = MFMA16(pa, vb1, ok[1]);
        ok[2] = MFMA16(pa, vb2, ok[2]);
        ok[3] = MFMA16(pa, vb3, ok[3]);
        __builtin_amdgcn_s_setprio(0);
    };

    stageA();                                   // tile 0
    asm volatile("s_waitcnt vmcnt(0)" ::: "memory");
    __builtin_amdgcn_s_barrier();

    for (int it = 0; it < 16; ++it) {
        stageB();                               // tile 2it+1
        compute(kbA, vbA);                      // tile 2it
        asm volatile("s_waitcnt vmcnt(0)" ::: "memory");
        __builtin_amdgcn_s_barrier();
        if (it < 15) stageA();                  // tile 2it+2
        compute(kbB, vbB);                      // tile 2it+1
        asm volatile("s_waitcnt vmcnt(0)" ::: "memory");
        __builtin_amdgcn_s_barrier();
    }

    // ---- merge k-halves: waves kh_=1 dump partials, waves kh_=0 combine ----
    __syncthreads();
    float* const obuf = (float*)&Kl[0][0];      // 2 x 1024 f32 (by q-half)
    float* const mlb  = (float*)&Vl[0][0];      // 2 x 64 f32
    if (kh_ == 1) {
        float* ob = obuf + qh_ * 1024;
        #pragma unroll
        for (int c = 0; c < 4; c++)
            #pragma unroll
            for (int r = 0; r < 4; r++)
                ob[(lg * 4 + r) * 64 + c * 16 + lq] = ok[c][r];
        if (lg == 0) {
            mlb[qh_ * 64 + lq]      = mrun;
            mlb[qh_ * 64 + 16 + lq] = lrun;
        }
    }
    __syncthreads();
    if (kh_ == 0) {
        const float* ob = obuf + qh_ * 1024;
        const float* ml = mlb + qh_ * 64;
        float fa[4], fb[4], linv[4];
        #pragma unroll
        for (int r = 0; r < 4; r++) {
            const int q = lg * 4 + r;
            const float ma = __shfl(mrun, q);
            const float la = __shfl(lrun, q);
            const float mb = ml[q];
            const float lb = ml[16 + q];
            const float ms = fmaxf(ma, mb);
            fa[r] = __expf(ma - ms);
            fb[r] = __expf(mb - ms);
            linv[r] = 1.f / (la * fa[r] + lb * fb[r]);
        }
        const int b = bh >> 3, h = bh & 7;
        #pragma unroll
        for (int c = 0; c < 4; c++)
            #pragma unroll
            for (int r = 0; r < 4; r++) {
                const int q = lg * 4 + r;
                const float v = (ok[c][r] * fa[r] + ob[q * 64 + c * 16 + lq] * fb[r]) * linv[r];
                const int qr = qt * 32 + qh_ * 16 + q;
                O[((size_t)(b * SEQ + qr)) * DM + h * DP + c * 16 + lq] = f2bf(v);
            }
    }
}

// ---------------------------------------------------------------------------
extern "C" void kernel_launch(void* const* d_in, const int* in_sizes, int n_in,
                              void* d_out, int out_size, void* d_ws, size_t ws_size,
                              hipStream_t stream) {
    const float* x  = (const float*)d_in[0];
    const float* Wq = (const float*)d_in[1];
    const float* bq = (const float*)d_in[2];
    const float* Wk = (const float*)d_in[3];
    const float* bk = (const float*)d_in[4];
    const float* Wv = (const float*)d_in[5];
    const float* bv = (const float*)d_in[6];
    const float* Wo = (const float*)d_in[7];
    const float* bo = (const float*)d_in[8];
    float* out = (float*)d_out;

    ushort16* ws   = (ushort16*)d_ws;
    ushort16* xb   = ws;
    ushort16* wqkv = xb + (size_t)MROWS * DM;
    ushort16* wob  = wqkv + (size_t)3 * DM * DM;
    ushort16* qh   = wob + (size_t)DM * DM;
    ushort16* kh   = qh + HEADS_ELEMS;
    ushort16* vt   = kh + HEADS_ELEMS;
    ushort16* oh   = vt + HEADS_ELEMS;

    convert_inputs<<<dim3((XF4 + 4 * WF4) / 256), dim3(256), 0, stream>>>(
        (const float4*)x, (const float4*)Wq, (const float4*)Wk,
        (const float4*)Wv, (const float4*)Wo,
        (ushort4*)xb, (ushort4*)wqkv, (ushort4*)wob);

    gemm_mfma<128, 128, 0><<<dim3(12, 32), dim3(256), 0, stream>>>(
        xb, wqkv, bq, bk, bv, bo, qh, kh, vt, nullptr);

    attn_mfma<<<dim3(1024), dim3(256), 0, stream>>>(qh, kh, vt, oh);

    gemm_mfma<64, 128, 1><<<dim3(4, 64), dim3(256), 0, stream>>>(
        oh, wob, bq, bk, bv, bo, qh, kh, vt, out);
}